// Round 12
// baseline (69.474 us; speedup 1.0000x reference)
//
#include <hip/hip_runtime.h>

#define NN 50000
#define NE 500000
#define DD 128
#define CAP 32                       // bucket capacity per dst (P(deg>32)~3e-9; spill exact)
#define SPILLCAP 4096
#define NTILE ((NN + 63) / 64)       // 782 gemm tiles

typedef __attribute__((ext_vector_type(8))) short bf16x8;
typedef __attribute__((ext_vector_type(4))) float f32x4;

// ---------------------------------------------------------------------------
// xs[n] = bf16( (x@W)[n] )   (12.8 MB gather table, unscaled)
// out[d] = relu( dinv[d]*(xs[d]*dinv[d] + sum_e xs[src]*dinv[src]) + b )
//   dinv[i] = rsqrtf(cnt[i]+1) inline from the degree histogram.
// Edges grouped by dst in ONE pass into int buckets col[d][0..CAP) (6.4 MB);
// overflow (never in practice) goes to an exact spill list.
// 3 launches: init -> {bucket-scatter || MFMA gemm, interleaved blocks} ->
// aggr (batch-8 pipelined gathers).
// ---------------------------------------------------------------------------

__device__ __forceinline__ unsigned int bf16pair(float a, float b) {
    unsigned int ua = __float_as_uint(a);
    ua = (ua + 0x7FFFu + ((ua >> 16) & 1u)) >> 16;   // RNE
    unsigned int ub = __float_as_uint(b);
    ub = (ub + 0x7FFFu + ((ub >> 16) & 1u)) >> 16;
    return ua | (ub << 16);
}
__device__ __forceinline__ float bflo(unsigned int u) { return __uint_as_float(u << 16); }
__device__ __forceinline__ float bfhi(unsigned int u) { return __uint_as_float(u & 0xFFFF0000u); }

// init: zero cnt + spill counter; repack W into B-fragment-linear bf16.
__global__ void k_init(const float* __restrict__ W, unsigned int* __restrict__ Wf,
                       int* __restrict__ cnt, int* __restrict__ spill_n) {
    int blk = blockIdx.x, t = threadIdx.x;
    if (blk < 8) {
        int id = blk * 256 + t;              // 0..2047
        int lane = id & 63;
        int ts = id >> 6;
        int t8 = ts >> 2, s = ts & 3;
        int col = t8 * 16 + (lane & 15);
        int k0 = s * 32 + (lane >> 4) * 8;
#pragma unroll
        for (int j = 0; j < 4; ++j) {
            float a = W[(k0 + 2 * j) * DD + col];
            float bb = W[(k0 + 2 * j + 1) * DD + col];
            Wf[id * 4 + j] = bf16pair(a, bb);
        }
    } else {
        int i = (blk - 8) * 256 + t;
        if (i < NN) cnt[i] = 0;
        if (i == NN) *spill_n = 0;
    }
}

// Fused: odd blocks scatter edges into dst buckets; even blocks run GEMM tiles
// (interleaved so hist atomics hide under gemm compute).
__global__ __launch_bounds__(256) void k_hist_gemm(
    const int* __restrict__ ei, int* __restrict__ cnt, int* __restrict__ col,
    int* __restrict__ spill, int* __restrict__ spill_n,
    const float* __restrict__ x, const unsigned int* __restrict__ Wf,
    unsigned short* __restrict__ xs, int n, int e) {
    const int blk = blockIdx.x, t = threadIdx.x;
    if (blk & 1) {  // ---- bucket scatter ----
        int i = (blk >> 1) * 256 + t;
        if (i >= e) return;
        bool is64 = (ei[1] == 0) & (ei[3] == 0) & (ei[5] == 0) & (ei[7] == 0);
        int s, d;
        if (is64) {
            s = ((const int2*)ei)[i].x;
            d = ((const int2*)ei)[e + i].x;
        } else {
            s = ei[i];
            d = ei[e + i];
        }
        int pos = atomicAdd(&cnt[d], 1);
        if (pos < CAP) {
            __builtin_nontemporal_store(s, &col[(size_t)d * CAP + pos]);
        } else {
            int sp = atomicAdd(spill_n, 1);
            if (sp < SPILLCAP) {
                spill[2 * sp] = d;
                spill[2 * sp + 1] = s;
            }
        }
        return;
    }
    // ---- GEMM tile: xs = bf16(x @ W) ----
    const int g = blk >> 1;
    if (g >= NTILE) return;
    const int wave = t >> 6, lane = t & 63;
    const int row0 = g * 64 + wave * 16;
    const int arow = min(row0 + (lane & 15), n - 1);
    const int kbase = (lane >> 4) * 8;

    bf16x8 af[4];
#pragma unroll
    for (int s = 0; s < 4; ++s) {
        const float* px = &x[(size_t)arow * DD + s * 32 + kbase];
        float4 a0 = *(const float4*)px;
        float4 a1 = *(const float4*)(px + 4);
        unsigned int p[4];
        p[0] = bf16pair(a0.x, a0.y);
        p[1] = bf16pair(a0.z, a0.w);
        p[2] = bf16pair(a1.x, a1.y);
        p[3] = bf16pair(a1.z, a1.w);
        af[s] = __builtin_bit_cast(bf16x8, *(f32x4*)p);
    }
    f32x4 acc[8] = {};
#pragma unroll
    for (int s = 0; s < 4; ++s) {
#pragma unroll
        for (int t8 = 0; t8 < 8; ++t8) {
            bf16x8 bf = *(const bf16x8*)&Wf[((t8 * 4 + s) * 64 + lane) * 4];
            acc[t8] = __builtin_amdgcn_mfma_f32_16x16x32_bf16(af[s], bf, acc[t8], 0, 0, 0);
        }
    }
    const int rrow0 = row0 + (lane >> 4) * 4;
    const int colb = lane & 15;
#pragma unroll
    for (int i = 0; i < 4; ++i) {
        int r = rrow0 + i;
        if (r < n) {
#pragma unroll
            for (int t8 = 0; t8 < 8; ++t8) {
                float v = acc[t8][i];
                unsigned int uv = __float_as_uint(v);
                uv = (uv + 0x7FFFu + ((uv >> 16) & 1u)) >> 16;
                xs[(size_t)r * DD + t8 * 16 + colb] = (unsigned short)uv;
            }
        }
    }
}

// Wave per dst; lane owns 1 dword (2 bf16 dims). Batch-8 pipelined gathers;
// dinv from cnt inline; int buckets.
__global__ __launch_bounds__(256) void k_aggr(
    const int* __restrict__ cnt, const int* __restrict__ col,
    const int* __restrict__ spill, const int* __restrict__ spill_n,
    const unsigned int* __restrict__ xs, const float* __restrict__ b,
    float* __restrict__ out) {
    int wid = (blockIdx.x * blockDim.x + threadIdx.x) >> 6;
    int lane = threadIdx.x & 63;
    if (wid >= NN) return;
    int deg = cnt[wid];
    float dvd = rsqrtf((float)deg + 1.0f);
    unsigned int u = xs[(size_t)wid * 64 + lane];
    float ax = bflo(u) * dvd, ay = bfhi(u) * dvd;   // self-loop term

    const int* myb = col + (size_t)wid * CAP;
    int nb = min(deg, CAP);
    for (int jb = 0; jb < nb; jb += 8) {
        int4 c0 = *(const int4*)&myb[jb];
        int4 c1 = *(const int4*)&myb[jb + 4];
        int sA[8] = {c0.x, c0.y, c0.z, c0.w, c1.x, c1.y, c1.z, c1.w};
        int cn[8];
        unsigned int uu[8];
#pragma unroll
        for (int k = 0; k < 8; ++k) {
            int s = (jb + k < nb) ? sA[k] : wid;   // dummy -> self row (cache-hot)
            cn[k] = cnt[s];
            uu[k] = xs[(size_t)s * 64 + lane];
        }
#pragma unroll
        for (int k = 0; k < 8; ++k) {
            float m = (jb + k < nb) ? rsqrtf((float)cn[k] + 1.0f) : 0.0f;
            ax = fmaf(bflo(uu[k]), m, ax);
            ay = fmaf(bfhi(uu[k]), m, ay);
        }
    }
    // exact spill fixup (expected empty)
    int ns = min(*spill_n, SPILLCAP);
    for (int k = 0; k < ns; ++k) {
        if (spill[2 * k] == wid) {
            int s = spill[2 * k + 1];
            float m = rsqrtf((float)cnt[s] + 1.0f);
            unsigned int us = xs[(size_t)s * 64 + lane];
            ax = fmaf(bflo(us), m, ax);
            ay = fmaf(bfhi(us), m, ay);
        }
    }
    float2 bb = *(const float2*)&b[lane * 2];
    float ox = fmaxf(fmaf(ax, dvd, bb.x), 0.f);
    float oy = fmaxf(fmaf(ay, dvd, bb.y), 0.f);
    *(float2*)&out[(size_t)wid * DD + lane * 2] = make_float2(ox, oy);
}

extern "C" void kernel_launch(void* const* d_in, const int* in_sizes, int n_in,
                              void* d_out, int out_size, void* d_ws, size_t ws_size,
                              hipStream_t stream) {
    const float* x  = (const float*)d_in[0];
    const int*   ei = (const int*)d_in[1];
    const float* W  = (const float*)d_in[2];
    const float* b  = (const float*)d_in[3];
    float* out = (float*)d_out;

    char* p = (char*)d_ws;
    unsigned short* xs      = (unsigned short*)p; p += (size_t)NN * DD * sizeof(unsigned short);
    int*            colW    = (int*)p;            p += (size_t)NN * CAP * sizeof(int);
    int*            cnt     = (int*)p;            p += NN * sizeof(int);
    int*            spill   = (int*)p;            p += 2 * SPILLCAP * sizeof(int);
    int*            spill_n = (int*)p;            p += sizeof(int);
    unsigned int*   Wf      = (unsigned int*)p;   p += 2048 * 4 * sizeof(unsigned int);

    const int nb_e = (NE + 255) / 256;            // 1954

    k_init<<<8 + (NN + 1 + 255) / 256, 256, 0, stream>>>(W, Wf, cnt, spill_n);
    k_hist_gemm<<<2 * nb_e, 256, 0, stream>>>(ei, cnt, colW, spill, spill_n,
                                              x, Wf, xs, NN, NE);
    k_aggr<<<(NN * 64 + 255) / 256, 256, 0, stream>>>(cnt, colW, spill, spill_n,
                                                      (const unsigned int*)xs, b, out);
}

// Round 13
// 65.901 us; speedup vs baseline: 1.0542x; 1.0542x over previous
//
#include <hip/hip_runtime.h>

#define NN 50000
#define NE 500000
#define DD 128
#define CAP 64                       // bucket capacity per dst (P(deg>64) ~ 1e-32)
#define SPILLCAP 4096
#define NTILE ((NN + 63) / 64)       // 782 gemm tiles

typedef __attribute__((ext_vector_type(8))) short bf16x8;
typedef __attribute__((ext_vector_type(4))) float f32x4;

// ---------------------------------------------------------------------------
// xs[n] = bf16( (x@W)[n] )   (12.8 MB gather table, unscaled)
// out[d] = relu( dinv[d]*(xs[d]*dinv[d] + sum_e xs[src]*dinv[src]) + b )
//   dinv[i] = rsqrtf(cnt[i]+1) inline from the degree histogram.
// Edges grouped by dst in ONE pass into int buckets col[d][0..CAP);
// overflow (never in practice) goes to an exact spill list.
// 3 launches: init -> {bucket-scatter || MFMA gemm, interleaved blocks} ->
// aggr (batch-8 pipelined gathers).  [R9 configuration — measured optimum]
// ---------------------------------------------------------------------------

__device__ __forceinline__ unsigned int bf16pair(float a, float b) {
    unsigned int ua = __float_as_uint(a);
    ua = (ua + 0x7FFFu + ((ua >> 16) & 1u)) >> 16;   // RNE
    unsigned int ub = __float_as_uint(b);
    ub = (ub + 0x7FFFu + ((ub >> 16) & 1u)) >> 16;
    return ua | (ub << 16);
}
__device__ __forceinline__ float bflo(unsigned int u) { return __uint_as_float(u << 16); }
__device__ __forceinline__ float bfhi(unsigned int u) { return __uint_as_float(u & 0xFFFF0000u); }

// init: zero cnt + spill counter; repack W into B-fragment-linear bf16.
__global__ void k_init(const float* __restrict__ W, unsigned int* __restrict__ Wf,
                       int* __restrict__ cnt, int* __restrict__ spill_n) {
    int blk = blockIdx.x, t = threadIdx.x;
    if (blk < 8) {
        int id = blk * 256 + t;              // 0..2047
        int lane = id & 63;
        int ts = id >> 6;
        int t8 = ts >> 2, s = ts & 3;
        int col = t8 * 16 + (lane & 15);
        int k0 = s * 32 + (lane >> 4) * 8;
#pragma unroll
        for (int j = 0; j < 4; ++j) {
            float a = W[(k0 + 2 * j) * DD + col];
            float bb = W[(k0 + 2 * j + 1) * DD + col];
            Wf[id * 4 + j] = bf16pair(a, bb);
        }
    } else {
        int i = (blk - 8) * 256 + t;
        if (i < NN) cnt[i] = 0;
        if (i == NN) *spill_n = 0;
    }
}

// Fused: odd blocks scatter edges into dst buckets; even blocks run GEMM tiles
// (interleaved so hist atomics hide under gemm compute).
__global__ __launch_bounds__(256) void k_hist_gemm(
    const int* __restrict__ ei, int* __restrict__ cnt, int* __restrict__ col,
    int* __restrict__ spill, int* __restrict__ spill_n,
    const float* __restrict__ x, const unsigned int* __restrict__ Wf,
    unsigned short* __restrict__ xs, int n, int e) {
    const int blk = blockIdx.x, t = threadIdx.x;
    if (blk & 1) {  // ---- bucket scatter ----
        int i = (blk >> 1) * 256 + t;
        if (i >= e) return;
        bool is64 = (ei[1] == 0) & (ei[3] == 0) & (ei[5] == 0) & (ei[7] == 0);
        int s, d;
        if (is64) {
            s = ((const int2*)ei)[i].x;
            d = ((const int2*)ei)[e + i].x;
        } else {
            s = ei[i];
            d = ei[e + i];
        }
        int pos = atomicAdd(&cnt[d], 1);
        if (pos < CAP) {
            col[(size_t)d * CAP + pos] = s;
        } else {
            int sp = atomicAdd(spill_n, 1);
            if (sp < SPILLCAP) {
                spill[2 * sp] = d;
                spill[2 * sp + 1] = s;
            }
        }
        return;
    }
    // ---- GEMM tile: xs = bf16(x @ W) ----
    const int g = blk >> 1;
    if (g >= NTILE) return;
    const int wave = t >> 6, lane = t & 63;
    const int row0 = g * 64 + wave * 16;
    const int arow = min(row0 + (lane & 15), n - 1);
    const int kbase = (lane >> 4) * 8;

    bf16x8 af[4];
#pragma unroll
    for (int s = 0; s < 4; ++s) {
        const float* px = &x[(size_t)arow * DD + s * 32 + kbase];
        float4 a0 = *(const float4*)px;
        float4 a1 = *(const float4*)(px + 4);
        unsigned int p[4];
        p[0] = bf16pair(a0.x, a0.y);
        p[1] = bf16pair(a0.z, a0.w);
        p[2] = bf16pair(a1.x, a1.y);
        p[3] = bf16pair(a1.z, a1.w);
        af[s] = __builtin_bit_cast(bf16x8, *(f32x4*)p);
    }
    f32x4 acc[8] = {};
#pragma unroll
    for (int s = 0; s < 4; ++s) {
#pragma unroll
        for (int t8 = 0; t8 < 8; ++t8) {
            bf16x8 bf = *(const bf16x8*)&Wf[((t8 * 4 + s) * 64 + lane) * 4];
            acc[t8] = __builtin_amdgcn_mfma_f32_16x16x32_bf16(af[s], bf, acc[t8], 0, 0, 0);
        }
    }
    const int rrow0 = row0 + (lane >> 4) * 4;
    const int colb = lane & 15;
#pragma unroll
    for (int i = 0; i < 4; ++i) {
        int r = rrow0 + i;
        if (r < n) {
#pragma unroll
            for (int t8 = 0; t8 < 8; ++t8) {
                float v = acc[t8][i];
                unsigned int uv = __float_as_uint(v);
                uv = (uv + 0x7FFFu + ((uv >> 16) & 1u)) >> 16;
                xs[(size_t)r * DD + t8 * 16 + colb] = (unsigned short)uv;
            }
        }
    }
}

// Wave per dst; lane owns 1 dword (2 bf16 dims). Batch-8 pipelined gathers;
// dinv from cnt inline; int buckets.
__global__ __launch_bounds__(256) void k_aggr(
    const int* __restrict__ cnt, const int* __restrict__ col,
    const int* __restrict__ spill, const int* __restrict__ spill_n,
    const unsigned int* __restrict__ xs, const float* __restrict__ b,
    float* __restrict__ out) {
    int wid = (blockIdx.x * blockDim.x + threadIdx.x) >> 6;
    int lane = threadIdx.x & 63;
    if (wid >= NN) return;
    int deg = cnt[wid];
    float dvd = rsqrtf((float)deg + 1.0f);
    unsigned int u = xs[(size_t)wid * 64 + lane];
    float ax = bflo(u) * dvd, ay = bfhi(u) * dvd;   // self-loop term

    const int* myb = col + (size_t)wid * CAP;
    int nb = min(deg, CAP);
    for (int jb = 0; jb < nb; jb += 8) {
        int4 c0 = *(const int4*)&myb[jb];
        int4 c1 = *(const int4*)&myb[jb + 4];
        int sA[8] = {c0.x, c0.y, c0.z, c0.w, c1.x, c1.y, c1.z, c1.w};
        int cn[8];
        unsigned int uu[8];
#pragma unroll
        for (int k = 0; k < 8; ++k) {
            int s = (jb + k < nb) ? sA[k] : wid;   // dummy -> self row (cache-hot)
            cn[k] = cnt[s];
            uu[k] = xs[(size_t)s * 64 + lane];
        }
#pragma unroll
        for (int k = 0; k < 8; ++k) {
            float m = (jb + k < nb) ? rsqrtf((float)cn[k] + 1.0f) : 0.0f;
            ax = fmaf(bflo(uu[k]), m, ax);
            ay = fmaf(bfhi(uu[k]), m, ay);
        }
    }
    // exact spill fixup (expected empty)
    int ns = min(*spill_n, SPILLCAP);
    for (int k = 0; k < ns; ++k) {
        if (spill[2 * k] == wid) {
            int s = spill[2 * k + 1];
            float m = rsqrtf((float)cnt[s] + 1.0f);
            unsigned int us = xs[(size_t)s * 64 + lane];
            ax = fmaf(bflo(us), m, ax);
            ay = fmaf(bfhi(us), m, ay);
        }
    }
    float2 bb = *(const float2*)&b[lane * 2];
    float ox = fmaxf(fmaf(ax, dvd, bb.x), 0.f);
    float oy = fmaxf(fmaf(ay, dvd, bb.y), 0.f);
    *(float2*)&out[(size_t)wid * DD + lane * 2] = make_float2(ox, oy);
}

extern "C" void kernel_launch(void* const* d_in, const int* in_sizes, int n_in,
                              void* d_out, int out_size, void* d_ws, size_t ws_size,
                              hipStream_t stream) {
    const float* x  = (const float*)d_in[0];
    const int*   ei = (const int*)d_in[1];
    const float* W  = (const float*)d_in[2];
    const float* b  = (const float*)d_in[3];
    float* out = (float*)d_out;

    char* p = (char*)d_ws;
    unsigned short* xs      = (unsigned short*)p; p += (size_t)NN * DD * sizeof(unsigned short);
    int*            colW    = (int*)p;            p += (size_t)NN * CAP * sizeof(int);
    int*            cnt     = (int*)p;            p += NN * sizeof(int);
    int*            spill   = (int*)p;            p += 2 * SPILLCAP * sizeof(int);
    int*            spill_n = (int*)p;            p += sizeof(int);
    unsigned int*   Wf      = (unsigned int*)p;   p += 2048 * 4 * sizeof(unsigned int);

    const int nb_e = (NE + 255) / 256;            // 1954

    k_init<<<8 + (NN + 1 + 255) / 256, 256, 0, stream>>>(W, Wf, cnt, spill_n);
    k_hist_gemm<<<2 * nb_e, 256, 0, stream>>>(ei, cnt, colW, spill, spill_n,
                                              x, Wf, xs, NN, NE);
    k_aggr<<<(NN * 64 + 255) / 256, 256, 0, stream>>>(cnt, colW, spill, spill_n,
                                                      (const unsigned int*)xs, b, out);
}